// Round 2
// 362.861 us; speedup vs baseline: 1.0368x; 1.0368x over previous
//
#include <hip/hip_runtime.h>
#include <cstdint>
#include <math.h>

#define L_SEQ 8192
#define DM    1024
#define NQK   2048          // fused Q,K output width

typedef unsigned short u16;
typedef __bf16 bf16;
typedef bf16  bf16x8 __attribute__((ext_vector_type(8)));
typedef float f32x4  __attribute__((ext_vector_type(4)));

__device__ __forceinline__ u16 f2bf(float f) {
    unsigned u = __float_as_uint(f);
    u += 0x7fffu + ((u >> 16) & 1u);
    return (u16)(u >> 16);
}

__device__ __forceinline__ f32x4 mfma16(bf16x8 a, bf16x8 b, f32x4 c) {
    return __builtin_amdgcn_mfma_f32_16x16x32_bf16(a, b, c, 0, 0, 0);
}

__device__ __forceinline__ void gld_lds16(const u16* g, u16* l) {
    __builtin_amdgcn_global_load_lds((const __attribute__((address_space(1))) void*)g,
                                     (__attribute__((address_space(3))) void*)l,
                                     16, 0, 0);
}

// raw barrier (no vmcnt drain) with compiler scheduling fence
__device__ __forceinline__ void bar() {
    __builtin_amdgcn_sched_barrier(0);
    __builtin_amdgcn_s_barrier();
    __builtin_amdgcn_sched_barrier(0);
}
#define VMCNT4() asm volatile("s_waitcnt vmcnt(4)" ::: "memory")
#define VMCNT0() asm volatile("s_waitcnt vmcnt(0)" ::: "memory")

// ---------------- fp32 -> bf16 conversion (8 elems / thread) ----------------
__global__ void cvt_bf16(const float* __restrict__ src, u16* __restrict__ dst, int n8) {
    int i = blockIdx.x * 256 + threadIdx.x;
    if (i >= n8) return;
    const float4* s4 = (const float4*)src;
    float4 a = s4[2 * i], b = s4[2 * i + 1];
    union { uint4 u; u16 h[8]; } r;
    r.h[0] = f2bf(a.x); r.h[1] = f2bf(a.y); r.h[2] = f2bf(a.z); r.h[3] = f2bf(a.w);
    r.h[4] = f2bf(b.x); r.h[5] = f2bf(b.y); r.h[6] = f2bf(b.z); r.h[7] = f2bf(b.w);
    ((uint4*)dst)[i] = r.u;
}

// ---------------- RoPE cos/sin table: [8192 pos][32 freq] float2 ------------
__global__ void rope_tbl(float2* __restrict__ t) {
    int idx = blockIdx.x * 256 + threadIdx.x;      // 0..262143
    int pos = idx >> 5, i = idx & 31;
    float invf = exp2f(-0.4152410118609191f * (float)i);   // 10000^(-i/32)
    float s, c;
    sincosf((float)pos * invf, &s, &c);
    t[idx] = make_float2(c, s);
}

// ============================================================================
// 256x256 tile, BK=64, 512 threads = 8 waves (2M x 4N), 8-phase counted-vmcnt
// schedule (2 K-tiles per 8 phases). LDS 128 KiB double buffer.
// Staging: A(u+1) halves at P1/P2, B(u+2) halves at P3/P4; vmcnt(4) at P4 only.
// ============================================================================

// staging macros: baseA/baseB are per-thread global src, ldsA/ldsB per-thread dst
#define STAGE_A(kt, ha, par) do { \
    gld_lds16(baseA + (size_t)(ha) * 131072 + (size_t)(kt) * 64, \
              ldsA + (par) * 16384 + (ha) * 8192); \
    gld_lds16(baseA + (size_t)(ha) * 131072 + 65536 + (size_t)(kt) * 64, \
              ldsA + (par) * 16384 + (ha) * 8192 + 4096); \
} while (0)
#define STAGE_B(kt, hb, par) do { \
    gld_lds16(baseB + (size_t)(hb) * 131072 + (size_t)(kt) * 64, \
              ldsB + (par) * 16384 + (hb) * 8192); \
    gld_lds16(baseB + (size_t)(hb) * 131072 + 65536 + (size_t)(kt) * 64, \
              ldsB + (par) * 16384 + (hb) * 8192 + 4096); \
} while (0)

// ---------------- Fused QKV GEMM ---------------------------------------------
// Y[m][0..2047] = (X*Wq^T | X*Wk^T) with RoPE; V slice (n0>=2048) is stored
// TRANSPOSED to Vt[(b*16+h)*64+d][seq].
__global__ __launch_bounds__(512, 2) void gemm_qkv_fused(
    const u16* __restrict__ X,        // [16384][1024]
    const u16* __restrict__ W,        // [3072][1024] rows: q,k,v stacked
    const float2* __restrict__ rope,  // [8192][32]
    u16* __restrict__ Y,              // [16384][2048]
    u16* __restrict__ Vt)             // [2*16*64][8192]
{
    __shared__ __align__(16) u16 smem[65536];   // 128 KiB
    u16* SA = smem;           // [2 par][2 half][128 row][8 chunk][8] bf16
    u16* SB = smem + 32768;

    // bijective XCD swizzle: 768 blocks, each XCD owns 96 contiguous ids
    int id = (int)blockIdx.x;
    id = (id & 7) * 96 + (id >> 3);
    const int n0 = (id % 12) * 256;
    const int m0 = (id / 12) * 256;

    const int tid = threadIdx.x;
    const int lane = tid & 63, w = tid >> 6;
    const int wm = w >> 2, wn = w & 3;          // 2M x 4N waves
    const int quad = lane >> 4, ln = lane & 15;

    // staging per-thread constants
    const int r0 = tid >> 3;                    // 0..63
    const int cgs = (tid & 7) ^ (r0 & 7);
    const u16* baseA = X + (size_t)(m0 + r0) * DM + cgs * 8;
    const u16* baseB = W + (size_t)(n0 + r0) * DM + cgs * 8;
    u16* ldsA = SA + tid * 8;
    u16* ldsB = SB + tid * 8;

    // fragment-read per-thread constants
    const int c0 = (quad ^ (ln & 7)) * 8;
    const int c1 = ((quad + 4) ^ (ln & 7)) * 8;
    const int aoff = wm * 8192 + ln * 64;
    const int boff = (wn >> 1) * 8192 + ((wn & 1) * 64 + ln) * 64;

    const f32x4 fz = {0.f, 0.f, 0.f, 0.f};
    f32x4 acc[8][4];
    #pragma unroll
    for (int a = 0; a < 8; a++)
        #pragma unroll
        for (int b = 0; b < 4; b++) acc[a][b] = fz;

    // prologue: tile0 A+B, tile1 B  (6 half-tiles / 12 loads)
    STAGE_A(0, 0, 0); STAGE_A(0, 1, 0);
    STAGE_B(0, 0, 0); STAGE_B(0, 1, 0);
    STAGE_B(1, 0, 1); STAGE_B(1, 1, 1);
    VMCNT4();
    bar();

    #pragma unroll 2
    for (int u = 0; u < 16; ++u) {
        const int par = u & 1;
        const u16* pa = SA + par * 16384 + aoff;
        const u16* pb = SB + par * 16384 + boff;
        bf16x8 af[4][2], bf[4][2];

        // ---- phase 1: quadrant (M0, N0) ----
        #pragma unroll
        for (int m = 0; m < 4; m++) {
            af[m][0] = *(const bf16x8*)(pa + m * 1024 + c0);
            af[m][1] = *(const bf16x8*)(pa + m * 1024 + c1);
        }
        #pragma unroll
        for (int n = 0; n < 2; n++) {
            bf[n][0] = *(const bf16x8*)(pb + n * 1024 + c0);
            bf[n][1] = *(const bf16x8*)(pb + n * 1024 + c1);
        }
        STAGE_A((u + 1) & 15, 0, par ^ 1);
        bar();
        __builtin_amdgcn_s_setprio(1);
        #pragma unroll
        for (int m = 0; m < 4; m++)
            #pragma unroll
            for (int n = 0; n < 2; n++) {
                acc[m][n] = mfma16(af[m][0], bf[n][0], acc[m][n]);
                acc[m][n] = mfma16(af[m][1], bf[n][1], acc[m][n]);
            }
        __builtin_amdgcn_s_setprio(0);
        bar();

        // ---- phase 2: quadrant (M0, N1) ----
        #pragma unroll
        for (int n = 0; n < 2; n++) {
            bf[2 + n][0] = *(const bf16x8*)(pb + (2 + n) * 1024 + c0);
            bf[2 + n][1] = *(const bf16x8*)(pb + (2 + n) * 1024 + c1);
        }
        STAGE_A((u + 1) & 15, 1, par ^ 1);
        bar();
        __builtin_amdgcn_s_setprio(1);
        #pragma unroll
        for (int m = 0; m < 4; m++)
            #pragma unroll
            for (int n = 0; n < 2; n++) {
                acc[m][2 + n] = mfma16(af[m][0], bf[2 + n][0], acc[m][2 + n]);
                acc[m][2 + n] = mfma16(af[m][1], bf[2 + n][1], acc[m][2 + n]);
            }
        __builtin_amdgcn_s_setprio(0);
        bar();

        // ---- phase 3: quadrant (M1, N1) ----
        #pragma unroll
        for (int m = 0; m < 4; m++) {
            af[m][0] = *(const bf16x8*)(pa + (4 + m) * 1024 + c0);
            af[m][1] = *(const bf16x8*)(pa + (4 + m) * 1024 + c1);
        }
        STAGE_B((u + 2) & 15, 0, par);
        bar();
        __builtin_amdgcn_s_setprio(1);
        #pragma unroll
        for (int m = 0; m < 4; m++)
            #pragma unroll
            for (int n = 0; n < 2; n++) {
                acc[4 + m][2 + n] = mfma16(af[m][0], bf[2 + n][0], acc[4 + m][2 + n]);
                acc[4 + m][2 + n] = mfma16(af[m][1], bf[2 + n][1], acc[4 + m][2 + n]);
            }
        __builtin_amdgcn_s_setprio(0);
        bar();

        // ---- phase 4: quadrant (M1, N0) ----
        STAGE_B((u + 2) & 15, 1, par);
        VMCNT4();
        bar();
        __builtin_amdgcn_s_setprio(1);
        #pragma unroll
        for (int m = 0; m < 4; m++)
            #pragma unroll
            for (int n = 0; n < 2; n++) {
                acc[4 + m][n] = mfma16(af[m][0], bf[n][0], acc[4 + m][n]);
                acc[4 + m][n] = mfma16(af[m][1], bf[n][1], acc[4 + m][n]);
            }
        __builtin_amdgcn_s_setprio(0);
        bar();
    }
    VMCNT0();
    bar();

    if (n0 < 2048) {
        // RoPE: wave covers one head's 64 cols; pair (i,i+32) = n-frags (nt,nt+2)
        #pragma unroll
        for (int mt = 0; mt < 8; mt++)
            #pragma unroll
            for (int reg = 0; reg < 4; reg++) {
                int rg = (m0 + wm * 128 + mt * 16 + quad * 4 + reg) & (L_SEQ - 1);
                const float2* rp = rope + rg * 32;
                #pragma unroll
                for (int nt = 0; nt < 2; nt++) {
                    float2 cs = rp[nt * 16 + ln];
                    float x1 = acc[mt][nt][reg], x2 = acc[mt][nt + 2][reg];
                    acc[mt][nt][reg]     = x1 * cs.x - x2 * cs.y;
                    acc[mt][nt + 2][reg] = x2 * cs.x + x1 * cs.y;
                }
            }
        // store via LDS, two 128-row passes
        u16* Es = smem;   // [128][264]
        #pragma unroll
        for (int mh = 0; mh < 2; mh++) {
            if (mh) __syncthreads();
            if (wm == mh) {
                #pragma unroll
                for (int mt = 0; mt < 8; mt++)
                    #pragma unroll
                    for (int nt = 0; nt < 4; nt++)
                        #pragma unroll
                        for (int reg = 0; reg < 4; reg++)
                            Es[(mt * 16 + quad * 4 + reg) * 264 + wn * 64 + nt * 16 + ln] =
                                f2bf(acc[mt][nt][reg]);
            }
            __syncthreads();
            #pragma unroll
            for (int i = 0; i < 8; i++) {
                int idx = i * 512 + tid;
                int row = idx >> 5, ch = (idx & 31) * 8;
                uint4 v = *(const uint4*)(Es + row * 264 + ch);
                *(uint4*)(Y + (size_t)(m0 + mh * 128 + row) * NQK + n0 + ch) = v;
            }
        }
    } else {
        // V slice: store TRANSPOSED. Two 128-col passes: Es[col][row]
        u16* Es = smem;   // [128][264]
        const int bb = m0 >> 13, seq0 = m0 & (L_SEQ - 1);
        #pragma unroll
        for (int nh = 0; nh < 2; nh++) {
            if (nh) __syncthreads();
            if ((wn >> 1) == nh) {
                #pragma unroll
                for (int mt = 0; mt < 8; mt++)
                    #pragma unroll
                    for (int nt = 0; nt < 4; nt++)
                        #pragma unroll
                        for (int reg = 0; reg < 4; reg++)
                            Es[((wn & 1) * 64 + nt * 16 + ln) * 264 + wm * 128 + mt * 16 + quad * 4 + reg] =
                                f2bf(acc[mt][nt][reg]);
            }
            __syncthreads();
            #pragma unroll
            for (int i = 0; i < 8; i++) {
                int idx = i * 512 + tid;
                int dr = idx >> 5, ch = (idx & 31) * 8;
                int gc = n0 - 2048 + nh * 128 + dr;      // global V col = h*64 + d
                uint4 v = *(const uint4*)(Es + dr * 264 + ch);
                *(uint4*)(Vt + (size_t)(bb * 1024 + gc) * L_SEQ + seq0 + ch) = v;
            }
        }
    }
}

// ---------------- Output projection: Out = A * Wo^T + bo, fp32 out ----------
__global__ __launch_bounds__(512, 2) void gemm_oproj(
    const u16* __restrict__ A,        // [16384][1024] bf16
    const u16* __restrict__ Wo,       // [1024][1024] bf16
    const float* __restrict__ bias,
    float* __restrict__ Out)
{
    __shared__ __align__(16) u16 smem[65536];   // 128 KiB
    u16* SA = smem;
    u16* SB = smem + 32768;

    int id = (int)blockIdx.x;                   // 256 blocks
    id = (id & 7) * 32 + (id >> 3);
    const int n0 = (id & 3) * 256;
    const int m0 = (id >> 2) * 256;

    const int tid = threadIdx.x;
    const int lane = tid & 63, w = tid >> 6;
    const int wm = w >> 2, wn = w & 3;
    const int quad = lane >> 4, ln = lane & 15;

    const int r0 = tid >> 3;
    const int cgs = (tid & 7) ^ (r0 & 7);
    const u16* baseA = A  + (size_t)(m0 + r0) * DM + cgs * 8;
    const u16* baseB = Wo + (size_t)(n0 + r0) * DM + cgs * 8;
    u16* ldsA = SA + tid * 8;
    u16* ldsB = SB + tid * 8;

    const int c0 = (quad ^ (ln & 7)) * 8;
    const int c1 = ((quad + 4) ^ (ln & 7)) * 8;
    const int aoff = wm * 8192 + ln * 64;
    const int boff = (wn >> 1) * 8192 + ((wn & 1) * 64 + ln) * 64;

    const f32x4 fz = {0.f, 0.f, 0.f, 0.f};
    f32x4 acc[8][4];
    #pragma unroll
    for (int a = 0; a < 8; a++)
        #pragma unroll
        for (int b = 0; b < 4; b++) acc[a][b] = fz;

    STAGE_A(0, 0, 0); STAGE_A(0, 1, 0);
    STAGE_B(0, 0, 0); STAGE_B(0, 1, 0);
    STAGE_B(1, 0, 1); STAGE_B(1, 1, 1);
    VMCNT4();
    bar();

    #pragma unroll 2
    for (int u = 0; u < 16; ++u) {
        const int par = u & 1;
        const u16* pa = SA + par * 16384 + aoff;
        const u16* pb = SB + par * 16384 + boff;
        bf16x8 af[4][2], bf[4][2];

        #pragma unroll
        for (int m = 0; m < 4; m++) {
            af[m][0] = *(const bf16x8*)(pa + m * 1024 + c0);
            af[m][1] = *(const bf16x8*)(pa + m * 1024 + c1);
        }
        #pragma unroll
        for (int n = 0; n < 2; n++) {
            bf[n][0] = *(const bf16x8*)(pb + n * 1024 + c0);
            bf[n][1] = *(const bf16x8*)(pb + n * 1024 + c1);
        }
        STAGE_A((u + 1) & 15, 0, par ^ 1);
        bar();
        __builtin_amdgcn_s_setprio(1);
        #pragma unroll
        for (int m = 0; m < 4; m++)
            #pragma unroll
            for (int n = 0; n < 2; n++) {
                acc[m][n] = mfma16(af[m][0], bf[n][0], acc[m][n]);
                acc[m][n] = mfma16(af[m][1], bf[n][1], acc[m][n]);
            }
        __builtin_amdgcn_s_setprio(0);
        bar();

        #pragma unroll
        for (int n = 0; n < 2; n++) {
            bf[2 + n][0] = *(const bf16x8*)(pb + (2 + n) * 1024 + c0);
            bf[2 + n][1] = *(const bf16x8*)(pb + (2 + n) * 1024 + c1);
        }
        STAGE_A((u + 1) & 15, 1, par ^ 1);
        bar();
        __builtin_amdgcn_s_setprio(1);
        #pragma unroll
        for (int m = 0; m < 4; m++)
            #pragma unroll
            for (int n = 0; n < 2; n++) {
                acc[m][2 + n] = mfma16(af[m][0], bf[2 + n][0], acc[m][2 + n]);
                acc[m][2 + n] = mfma16(af[m][1], bf[2 + n][1], acc[m][2 + n]);
            }
        __builtin_amdgcn_s_setprio(0);
        bar();

        #pragma unroll
        for (int m = 0; m < 4; m++) {
            af[m][0] = *(const bf16x8*)(pa + (4 + m) * 1024 + c0);
            af[m][1] = *(const bf16x8*)(pa + (4 + m) * 1024 + c1);
        }
        STAGE_B((u + 2) & 15, 0, par);
        bar();
        __builtin_amdgcn_s_setprio(1);
        #pragma unroll
        for (int m = 0; m < 4; m++)
            #pragma unroll
            for (int n = 0; n < 2; n++) {
                acc[4 + m][2 + n] = mfma16(af[m][0], bf[2 + n][0], acc[4 + m][2 + n]);
                acc[4 + m][2 + n] = mfma16(af[m][1], bf[2 + n][1], acc[4 + m][2 + n]);
            }
        __builtin_amdgcn_s_setprio(0);
        bar();

        STAGE_B((u + 2) & 15, 1, par);
        VMCNT4();
        bar();
        __builtin_amdgcn_s_setprio(1);
        #pragma unroll
        for (int m = 0; m < 4; m++)
            #pragma unroll
            for (int n = 0; n < 2; n++) {
                acc[4 + m][n] = mfma16(af[m][0], bf[n][0], acc[4 + m][n]);
                acc[4 + m][n] = mfma16(af[m][1], bf[n][1], acc[4 + m][n]);
            }
        __builtin_amdgcn_s_setprio(0);
        bar();
    }
    VMCNT0();
    bar();

    // epilogue: bias + fp32 store via LDS, four 64-row passes
    float b4[4];
    #pragma unroll
    for (int nt = 0; nt < 4; nt++) b4[nt] = bias[n0 + wn * 64 + nt * 16 + ln];

    float* Ef = (float*)smem;   // [64][260]
    #pragma unroll
    for (int mq = 0; mq < 4; mq++) {
        if (mq) __syncthreads();
        if (wm == (mq >> 1)) {
            #pragma unroll
            for (int mt = 0; mt < 4; mt++)
                #pragma unroll
                for (int nt = 0; nt < 4; nt++)
                    #pragma unroll
                    for (int reg = 0; reg < 4; reg++)
                        Ef[(mt * 16 + quad * 4 + reg) * 260 + wn * 64 + nt * 16 + ln] =
                            acc[(mq & 1) * 4 + mt][nt][reg] + b4[nt];
        }
        __syncthreads();
        #pragma unroll
        for (int i = 0; i < 8; i++) {
            int idx = i * 512 + tid;
            int row = idx >> 6, ch = (idx & 63) * 4;
            float4 v = *(const float4*)(Ef + row * 260 + ch);
            *(float4*)(Out + (size_t)(m0 + mq * 64 + row) * DM + n0 + ch) = v;
        }
    }
}

// ---------------- Windowed attention ----------------------------------------
// WG = 512 threads / 8 waves = 128 queries x 1 head. grid (64, 16, 2).
// K and V^T staged once per WG via global_load_lds (XOR chunk swizzle).
__global__ __launch_bounds__(512, 4) void attn(
    const u16* __restrict__ QK,       // [16384][2048]
    const u16* __restrict__ Vt,       // [2048][8192]
    u16* __restrict__ AO)             // [16384][1024]
{
    __shared__ __align__(16) u16 Ks[256 * 64];     // [key][dim-chunk swizzled] 32KB (aliased by AOs)
    __shared__ __align__(16) u16 Vs[64 * 256];     // [dim][key-chunk swizzled] 32KB
    __shared__ __align__(16) u16 pbuf[8][512];     // per-wave P chunk, xor-swizzled

    const int blk = blockIdx.x;
    const int h   = blockIdx.y;
    const int b   = blockIdx.z;
    const int tid = threadIdx.x;
    const int lane = tid & 63, w = tid >> 6;
    const int quad = lane >> 4, ln = lane & 15;
    const int wstart = blk * 128 - 64;
    const size_t bbase = (size_t)b * L_SEQ;

    const u16* Kg = QK + 1024 + h * 64;
    const u16* Vg = Vt + (size_t)(b * 1024 + h * 64) * L_SEQ;

    // stage K: 256 rows x 8 chunks, chunk cg = cl ^ (row&7)
    #pragma unroll
    for (int i = 0; i < 4; i++) {
        int c = i * 512 + tid;
        int row = c >> 3, cl = c & 7, cg = cl ^ (row & 7);
        int kr = wstart + row;
        kr = kr < 0 ? 0 : (kr > L_SEQ - 1 ? L_SEQ - 1 : kr);
        gld_lds16(Kg + (size_t)(bbase + kr) * NQK + cg * 8, Ks + c * 8);
    }
    // stage V^T: 64 dim-rows x 32 key-chunks, chunk cg = kc ^ (d&7)
    #pragma unroll
    for (int i = 0; i < 4; i++) {
        int c = i * 512 + tid;
        int d = c >> 5, kc = c & 31, cg = kc ^ (d & 7);
        int key = wstart + cg * 8;
        key = key < 0 ? 0 : (key > L_SEQ - 8 ? L_SEQ - 8 : key);
        gld_lds16(Vg + (size_t)d * L_SEQ + key, Vs + c * 8);
    }

    // Q fragments (A-layout: m=ln, k=quad*8+j) direct from global
    const int qrow = blk * 128 + w * 16 + ln;
    const u16* qp = QK + (bbase + qrow) * NQK + h * 64 + quad * 8;
    bf16x8 aq0 = *(const bf16x8*)qp;
    bf16x8 aq1 = *(const bf16x8*)(qp + 32);
    __syncthreads();

    // scores: 16 n-tiles x 16 keys
    const f32x4 fz = {0.f, 0.f, 0.f, 0.f};
    f32x4 s[16];
    #pragma unroll
    for (int nt = 0; nt < 16; nt++) {
        int row = nt * 16 + ln;
        bf16x8 b0 = *(const bf16x8*)(Ks + row * 64 + ((quad       ^ (ln & 7)) * 8));
        bf16x8 b1 = *(const bf16x8*)(Ks + row * 64 + (((4 + quad) ^ (ln & 7)) * 8));
        f32x4 t = mfma16(aq0, b0, fz);
        t = mfma16(aq1, b1, t);
        s[nt] = t;
    }
    __syncthreads();   // all Ks reads done before AOs (alias) writes

    // softmax; row = quad*4+r, col key = wstart + nt*16 + ln
    const float SC = 0.125f * 1.4426950408889634f;   // /sqrt(64) * log2(e)
    float mr[4] = {-INFINITY, -INFINITY, -INFINITY, -INFINITY};
    #pragma unroll
    for (int nt = 0; nt < 16; nt++) {
        int key = wstart + nt * 16 + ln;
        bool valid = (key >= 0) && (key < L_SEQ);
        #pragma unroll
        for (int r = 0; r < 4; r++) {
            float v = valid ? s[nt][r] * SC : -INFINITY;
            s[nt][r] = v;
            mr[r] = fmaxf(mr[r], v);
        }
    }
    #pragma unroll
    for (int off = 1; off < 16; off <<= 1)
        #pragma unroll
        for (int r = 0; r < 4; r++) mr[r] = fmaxf(mr[r], __shfl_xor(mr[r], off));

    float lr[4] = {0.f, 0.f, 0.f, 0.f};
    #pragma unroll
    for (int nt = 0; nt < 16; nt++)
        #pragma unroll
        for (int r = 0; r < 4; r++) {
            float p = exp2f(s[nt][r] - mr[r]);   // exp2(-inf)=0 on masked cols
            s[nt][r] = p;
            lr[r] += p;
        }
    #pragma unroll
    for (int off = 1; off < 16; off <<= 1)
        #pragma unroll
        for (int r = 0; r < 4; r++) lr[r] += __shfl_xor(lr[r], off);
    float rl[4];
    #pragma unroll
    for (int r = 0; r < 4; r++) rl[r] = 1.f / lr[r];

    // PV: per 32-key chunk, C-layout -> A-layout via xor-swizzled per-wave LDS
    u16* pb = pbuf[w];
    f32x4 o[4] = {fz, fz, fz, fz};
    #pragma unroll
    for (int ks = 0; ks < 8; ks++) {
        #pragma unroll
        for (int n2 = 0; n2 < 2; n2++) {
            int nt = ks * 2 + n2;
            #pragma unroll
            for (int r = 0; r < 4; r++)
                pb[(quad * 4 + r) * 32 + ((n2 * 16 + ln) ^ (quad * 8))] = f2bf(s[nt][r]);
        }
        bf16x8 ap = *(const bf16x8*)(pb + ln * 32 + ((quad * 8) ^ (((ln >> 2) & 3) * 8)));
        #pragma unroll
        for (int dt = 0; dt < 4; dt++) {
            int d = dt * 16 + ln;
            bf16x8 vb = *(const bf16x8*)(Vs + d * 256 + (((ks * 4 + quad) ^ (ln & 7)) * 8));
            o[dt] = mfma16(ap, vb, o[dt]);
        }
    }

    // AO through LDS (alias Ks) for coalesced 16B stores
    u16* AOs = Ks;   // [128][72]
    #pragma unroll
    for (int dt = 0; dt < 4; dt++)
        #pragma unroll
        for (int r = 0; r < 4; r++)
            AOs[(w * 16 + quad * 4 + r) * 72 + dt * 16 + ln] = f2bf(o[dt][r] * rl[r]);
    __syncthreads();
    #pragma unroll
    for (int i = 0; i < 2; i++) {
        int c = i * 512 + tid;
        int row = c >> 3, ch = (c & 7) * 8;
        uint4 v = *(const uint4*)(AOs + row * 72 + ch);
        *(uint4*)(AO + (bbase + blk * 128 + row) * DM + h * 64 + ch) = v;
    }
}

// ---------------------------------------------------------------------------
extern "C" void kernel_launch(void* const* d_in, const int* in_sizes, int n_in,
                              void* d_out, int out_size, void* d_ws, size_t ws_size,
                              hipStream_t stream) {
    const float* x  = (const float*)d_in[0];
    const float* wq = (const float*)d_in[1];
    const float* wk = (const float*)d_in[2];
    const float* wv = (const float*)d_in[3];
    const float* wo = (const float*)d_in[4];
    const float* bo = (const float*)d_in[5];
    float* out = (float*)d_out;

    char* ws = (char*)d_ws;
    const size_t MB = 1024 * 1024;
    u16*   xb  = (u16*)ws;                       // 32 MB  [16384][1024] bf16
    u16*   fqk = (u16*)(ws + 32 * MB);           // 64 MB  [16384][2048] bf16 (Q|K)
    u16*   vt  = (u16*)(ws + 96 * MB);           // 32 MB  [2048][8192] bf16 (V^T)
    u16*   wf  = (u16*)(ws + 128 * MB);          // 6 MB   [3072][1024] bf16 (q,k,v stacked)
    float2* rt = (float2*)(ws + 134 * MB);       // 2 MB   [8192][32] cos/sin
    u16*   wob = (u16*)(ws + 136 * MB);          // 2 MB   [1024][1024] bf16
    u16*   aob = xb;   // x dead after fused GEMM; alias attention output over it

    cvt_bf16<<<8192, 256, 0, stream>>>(x, xb, 2097152);
    cvt_bf16<<<512, 256, 0, stream>>>(wq, wf, 131072);
    cvt_bf16<<<512, 256, 0, stream>>>(wk, wf + 1024 * 1024, 131072);
    cvt_bf16<<<512, 256, 0, stream>>>(wv, wf + 2 * 1024 * 1024, 131072);
    cvt_bf16<<<512, 256, 0, stream>>>(wo, wob, 131072);
    rope_tbl<<<1024, 256, 0, stream>>>(rt);

    gemm_qkv_fused<<<768, 512, 0, stream>>>(xb, wf, rt, fqk, vt);
    attn<<<dim3(64, 16, 2), 512, 0, stream>>>(fqk, vt, aob);
    gemm_oproj<<<256, 512, 0, stream>>>(aob, wob, bo, out);
}

// Round 3
// 343.372 us; speedup vs baseline: 1.0957x; 1.0568x over previous
//
#include <hip/hip_runtime.h>
#include <cstdint>
#include <math.h>

#define L_SEQ 8192
#define DM    1024
#define NQK   2048          // fused Q,K output width

typedef unsigned short u16;
typedef __bf16 bf16;
typedef bf16  bf16x8 __attribute__((ext_vector_type(8)));
typedef float f32x4  __attribute__((ext_vector_type(4)));

__device__ __forceinline__ u16 f2bf(float f) {
    unsigned u = __float_as_uint(f);
    u += 0x7fffu + ((u >> 16) & 1u);
    return (u16)(u >> 16);
}

__device__ __forceinline__ f32x4 mfma16(bf16x8 a, bf16x8 b, f32x4 c) {
    return __builtin_amdgcn_mfma_f32_16x16x32_bf16(a, b, c, 0, 0, 0);
}

__device__ __forceinline__ void gld_lds16(const u16* g, u16* l) {
    __builtin_amdgcn_global_load_lds((const __attribute__((address_space(1))) void*)g,
                                     (__attribute__((address_space(3))) void*)l,
                                     16, 0, 0);
}

// raw barrier (no vmcnt drain, no scheduler fence)
__device__ __forceinline__ void bar() {
    __builtin_amdgcn_s_barrier();
}
#define VMCNT4() asm volatile("s_waitcnt vmcnt(4)" ::: "memory")
#define VMCNT0() asm volatile("s_waitcnt vmcnt(0)" ::: "memory")

// ---------------- fp32 -> bf16 conversion (8 elems / thread) ----------------
__global__ void cvt_bf16(const float* __restrict__ src, u16* __restrict__ dst, int n8) {
    int i = blockIdx.x * 256 + threadIdx.x;
    if (i >= n8) return;
    const float4* s4 = (const float4*)src;
    float4 a = s4[2 * i], b = s4[2 * i + 1];
    union { uint4 u; u16 h[8]; } r;
    r.h[0] = f2bf(a.x); r.h[1] = f2bf(a.y); r.h[2] = f2bf(a.z); r.h[3] = f2bf(a.w);
    r.h[4] = f2bf(b.x); r.h[5] = f2bf(b.y); r.h[6] = f2bf(b.z); r.h[7] = f2bf(b.w);
    ((uint4*)dst)[i] = r.u;
}

// ---------------- RoPE cos/sin table: [8192 pos][32 freq] float2 ------------
__global__ void rope_tbl(float2* __restrict__ t) {
    int idx = blockIdx.x * 256 + threadIdx.x;      // 0..262143
    int pos = idx >> 5, i = idx & 31;
    float invf = exp2f(-0.4152410118609191f * (float)i);   // 10000^(-i/32)
    float s, c;
    sincosf((float)pos * invf, &s, &c);
    t[idx] = make_float2(c, s);
}

// ============================================================================
// 256x256 tile, BK=64, 512 threads = 8 waves (2M x 4N), 8-phase counted-vmcnt
// schedule (2 K-tiles per 8 phases). LDS 128 KiB double buffer.
// Staging: A(u+1) halves at P1/P2, B(u+2) halves at P3/P4; vmcnt(4) at P4 only.
// XCD supertiling: XCD x owns m-panels [8x,8x+8) for ALL n; within an XCD,
// supertiles of 8m x 4n = 32 blocks (the concurrent set): B working set 2MB +
// A 4MB fits L2; A panels persist across supertiles.
// ============================================================================

// staging macros: baseA/baseB are per-thread global src, ldsA/ldsB per-thread dst
#define STAGE_A(kt, ha, par) do { \
    gld_lds16(baseA + (size_t)(ha) * 131072 + (size_t)(kt) * 64, \
              ldsA + (par) * 16384 + (ha) * 8192); \
    gld_lds16(baseA + (size_t)(ha) * 131072 + 65536 + (size_t)(kt) * 64, \
              ldsA + (par) * 16384 + (ha) * 8192 + 4096); \
} while (0)
#define STAGE_B(kt, hb, par) do { \
    gld_lds16(baseB + (size_t)(hb) * 131072 + (size_t)(kt) * 64, \
              ldsB + (par) * 16384 + (hb) * 8192); \
    gld_lds16(baseB + (size_t)(hb) * 131072 + 65536 + (size_t)(kt) * 64, \
              ldsB + (par) * 16384 + (hb) * 8192 + 4096); \
} while (0)

// ---------------- Fused QKV GEMM ---------------------------------------------
__global__ __launch_bounds__(512, 2) void gemm_qkv_fused(
    const u16* __restrict__ X,        // [16384][1024]
    const u16* __restrict__ W,        // [3072][1024] rows: q,k,v stacked
    const float2* __restrict__ rope,  // [8192][32]
    u16* __restrict__ Y,              // [16384][2048]
    u16* __restrict__ Vt)             // [2*16*64][8192]
{
    __shared__ __align__(16) u16 smem[65536];   // 128 KiB
    u16* SA = smem;           // [2 par][2 half][128 row][8 chunk][8] bf16
    u16* SB = smem + 32768;

    // XCD supertile swizzle: o -> (xcd, supertile, n_local, m_local)
    {
    }
    const int o   = (int)blockIdx.x;            // 768 blocks
    const int xcd = o & 7;
    const int r   = o >> 3;                     // 0..95, temporal order in XCD
    const int st  = r >> 5;                     // 3 supertiles of 32
    const int t   = r & 31;
    const int m0  = (xcd * 8 + (t & 7)) * 256;  // m panel 0..63
    const int n0  = (st * 4 + (t >> 3)) * 256;  // n panel 0..11

    const int tid = threadIdx.x;
    const int lane = tid & 63, w = tid >> 6;
    const int wm = w >> 2, wn = w & 3;          // 2M x 4N waves
    const int quad = lane >> 4, ln = lane & 15;

    // staging per-thread constants
    const int r0 = tid >> 3;                    // 0..63
    const int cgs = (tid & 7) ^ (r0 & 7);
    const u16* baseA = X + (size_t)(m0 + r0) * DM + cgs * 8;
    const u16* baseB = W + (size_t)(n0 + r0) * DM + cgs * 8;
    u16* ldsA = SA + tid * 8;
    u16* ldsB = SB + tid * 8;

    // fragment-read per-thread constants
    const int c0 = (quad ^ (ln & 7)) * 8;
    const int c1 = ((quad + 4) ^ (ln & 7)) * 8;
    const int aoff = wm * 8192 + ln * 64;
    const int boff = (wn >> 1) * 8192 + ((wn & 1) * 64 + ln) * 64;

    const f32x4 fz = {0.f, 0.f, 0.f, 0.f};
    f32x4 acc[8][4];
    #pragma unroll
    for (int a = 0; a < 8; a++)
        #pragma unroll
        for (int b = 0; b < 4; b++) acc[a][b] = fz;

    // prologue: tile0 A+B, tile1 B  (6 half-tiles / 12 loads)
    STAGE_A(0, 0, 0); STAGE_A(0, 1, 0);
    STAGE_B(0, 0, 0); STAGE_B(0, 1, 0);
    STAGE_B(1, 0, 1); STAGE_B(1, 1, 1);
    VMCNT4();
    bar();

    #pragma unroll 2
    for (int u = 0; u < 16; ++u) {
        const int par = u & 1;
        const u16* pa = SA + par * 16384 + aoff;
        const u16* pb = SB + par * 16384 + boff;
        bf16x8 af[4][2], bf[4][2];

        // ---- phase 1: quadrant (M0, N0) ----
        #pragma unroll
        for (int m = 0; m < 4; m++) {
            af[m][0] = *(const bf16x8*)(pa + m * 1024 + c0);
            af[m][1] = *(const bf16x8*)(pa + m * 1024 + c1);
        }
        #pragma unroll
        for (int n = 0; n < 2; n++) {
            bf[n][0] = *(const bf16x8*)(pb + n * 1024 + c0);
            bf[n][1] = *(const bf16x8*)(pb + n * 1024 + c1);
        }
        STAGE_A((u + 1) & 15, 0, par ^ 1);
        bar();
        __builtin_amdgcn_s_setprio(1);
        #pragma unroll
        for (int m = 0; m < 4; m++)
            #pragma unroll
            for (int n = 0; n < 2; n++) {
                acc[m][n] = mfma16(af[m][0], bf[n][0], acc[m][n]);
                acc[m][n] = mfma16(af[m][1], bf[n][1], acc[m][n]);
            }
        __builtin_amdgcn_s_setprio(0);
        bar();

        // ---- phase 2: quadrant (M0, N1) ----
        #pragma unroll
        for (int n = 0; n < 2; n++) {
            bf[2 + n][0] = *(const bf16x8*)(pb + (2 + n) * 1024 + c0);
            bf[2 + n][1] = *(const bf16x8*)(pb + (2 + n) * 1024 + c1);
        }
        STAGE_A((u + 1) & 15, 1, par ^ 1);
        bar();
        __builtin_amdgcn_s_setprio(1);
        #pragma unroll
        for (int m = 0; m < 4; m++)
            #pragma unroll
            for (int n = 0; n < 2; n++) {
                acc[m][2 + n] = mfma16(af[m][0], bf[2 + n][0], acc[m][2 + n]);
                acc[m][2 + n] = mfma16(af[m][1], bf[2 + n][1], acc[m][2 + n]);
            }
        __builtin_amdgcn_s_setprio(0);
        bar();

        // ---- phase 3: quadrant (M1, N1) ----
        #pragma unroll
        for (int m = 0; m < 4; m++) {
            af[m][0] = *(const bf16x8*)(pa + (4 + m) * 1024 + c0);
            af[m][1] = *(const bf16x8*)(pa + (4 + m) * 1024 + c1);
        }
        STAGE_B((u + 2) & 15, 0, par);
        bar();
        __builtin_amdgcn_s_setprio(1);
        #pragma unroll
        for (int m = 0; m < 4; m++)
            #pragma unroll
            for (int n = 0; n < 2; n++) {
                acc[4 + m][2 + n] = mfma16(af[m][0], bf[2 + n][0], acc[4 + m][2 + n]);
                acc[4 + m][2 + n] = mfma16(af[m][1], bf[2 + n][1], acc[4 + m][2 + n]);
            }
        __builtin_amdgcn_s_setprio(0);
        bar();

        // ---- phase 4: quadrant (M1, N0) ----
        STAGE_B((u + 2) & 15, 1, par);
        VMCNT4();
        bar();
        __builtin_amdgcn_s_setprio(1);
        #pragma unroll
        for (int m = 0; m < 4; m++)
            #pragma unroll
            for (int n = 0; n < 2; n++) {
                acc[4 + m][n] = mfma16(af[m][0], bf[n][0], acc[4 + m][n]);
                acc[4 + m][n] = mfma16(af[m][1], bf[n][1], acc[4 + m][n]);
            }
        __builtin_amdgcn_s_setprio(0);
        bar();
    }
    VMCNT0();
    bar();

    if (n0 < 2048) {
        // RoPE: wave covers one head's 64 cols; pair (i,i+32) = n-frags (nt,nt+2)
        #pragma unroll
        for (int mt = 0; mt < 8; mt++)
            #pragma unroll
            for (int reg = 0; reg < 4; reg++) {
                int rg = (m0 + wm * 128 + mt * 16 + quad * 4 + reg) & (L_SEQ - 1);
                const float2* rp = rope + rg * 32;
                #pragma unroll
                for (int nt = 0; nt < 2; nt++) {
                    float2 cs = rp[nt * 16 + ln];
                    float x1 = acc[mt][nt][reg], x2 = acc[mt][nt + 2][reg];
                    acc[mt][nt][reg]     = x1 * cs.x - x2 * cs.y;
                    acc[mt][nt + 2][reg] = x2 * cs.x + x1 * cs.y;
                }
            }
        // store via LDS, two 128-row passes
        u16* Es = smem;   // [128][264]
        #pragma unroll
        for (int mh = 0; mh < 2; mh++) {
            if (mh) __syncthreads();
            if (wm == mh) {
                #pragma unroll
                for (int mt = 0; mt < 8; mt++)
                    #pragma unroll
                    for (int nt = 0; nt < 4; nt++)
                        #pragma unroll
                        for (int reg = 0; reg < 4; reg++)
                            Es[(mt * 16 + quad * 4 + reg) * 264 + wn * 64 + nt * 16 + ln] =
                                f2bf(acc[mt][nt][reg]);
            }
            __syncthreads();
            #pragma unroll
            for (int i = 0; i < 8; i++) {
                int idx = i * 512 + tid;
                int row = idx >> 5, ch = (idx & 31) * 8;
                uint4 v = *(const uint4*)(Es + row * 264 + ch);
                *(uint4*)(Y + (size_t)(m0 + mh * 128 + row) * NQK + n0 + ch) = v;
            }
        }
    } else {
        // V slice: store TRANSPOSED. Two 128-col passes: Es[col][row]
        u16* Es = smem;   // [128][264]
        const int bb = m0 >> 13, seq0 = m0 & (L_SEQ - 1);
        #pragma unroll
        for (int nh = 0; nh < 2; nh++) {
            if (nh) __syncthreads();
            if ((wn >> 1) == nh) {
                #pragma unroll
                for (int mt = 0; mt < 8; mt++)
                    #pragma unroll
                    for (int nt = 0; nt < 4; nt++)
                        #pragma unroll
                        for (int reg = 0; reg < 4; reg++)
                            Es[((wn & 1) * 64 + nt * 16 + ln) * 264 + wm * 128 + mt * 16 + quad * 4 + reg] =
                                f2bf(acc[mt][nt][reg]);
            }
            __syncthreads();
            #pragma unroll
            for (int i = 0; i < 8; i++) {
                int idx = i * 512 + tid;
                int dr = idx >> 5, ch = (idx & 31) * 8;
                int gc = n0 - 2048 + nh * 128 + dr;      // global V col = h*64 + d
                uint4 v = *(const uint4*)(Es + dr * 264 + ch);
                *(uint4*)(Vt + (size_t)(bb * 1024 + gc) * L_SEQ + seq0 + ch) = v;
            }
        }
    }
}

// ---------------- Output projection: Out = A * Wo^T + bo, fp32 out ----------
__global__ __launch_bounds__(512, 2) void gemm_oproj(
    const u16* __restrict__ A,        // [16384][1024] bf16
    const u16* __restrict__ Wo,       // [1024][1024] bf16
    const float* __restrict__ bias,
    float* __restrict__ Out)
{
    __shared__ __align__(16) u16 smem[65536];   // 128 KiB
    u16* SA = smem;
    u16* SB = smem + 32768;

    // XCD supertile: one 8m x 4n supertile per XCD (256 blocks total)
    const int o   = (int)blockIdx.x;
    const int xcd = o & 7;
    const int t   = o >> 3;                     // 0..31
    const int m0  = (xcd * 8 + (t & 7)) * 256;
    const int n0  = (t >> 3) * 256;

    const int tid = threadIdx.x;
    const int lane = tid & 63, w = tid >> 6;
    const int wm = w >> 2, wn = w & 3;
    const int quad = lane >> 4, ln = lane & 15;

    const int r0 = tid >> 3;
    const int cgs = (tid & 7) ^ (r0 & 7);
    const u16* baseA = A  + (size_t)(m0 + r0) * DM + cgs * 8;
    const u16* baseB = Wo + (size_t)(n0 + r0) * DM + cgs * 8;
    u16* ldsA = SA + tid * 8;
    u16* ldsB = SB + tid * 8;

    const int c0 = (quad ^ (ln & 7)) * 8;
    const int c1 = ((quad + 4) ^ (ln & 7)) * 8;
    const int aoff = wm * 8192 + ln * 64;
    const int boff = (wn >> 1) * 8192 + ((wn & 1) * 64 + ln) * 64;

    const f32x4 fz = {0.f, 0.f, 0.f, 0.f};
    f32x4 acc[8][4];
    #pragma unroll
    for (int a = 0; a < 8; a++)
        #pragma unroll
        for (int b = 0; b < 4; b++) acc[a][b] = fz;

    STAGE_A(0, 0, 0); STAGE_A(0, 1, 0);
    STAGE_B(0, 0, 0); STAGE_B(0, 1, 0);
    STAGE_B(1, 0, 1); STAGE_B(1, 1, 1);
    VMCNT4();
    bar();

    #pragma unroll 2
    for (int u = 0; u < 16; ++u) {
        const int par = u & 1;
        const u16* pa = SA + par * 16384 + aoff;
        const u16* pb = SB + par * 16384 + boff;
        bf16x8 af[4][2], bf[4][2];

        #pragma unroll
        for (int m = 0; m < 4; m++) {
            af[m][0] = *(const bf16x8*)(pa + m * 1024 + c0);
            af[m][1] = *(const bf16x8*)(pa + m * 1024 + c1);
        }
        #pragma unroll
        for (int n = 0; n < 2; n++) {
            bf[n][0] = *(const bf16x8*)(pb + n * 1024 + c0);
            bf[n][1] = *(const bf16x8*)(pb + n * 1024 + c1);
        }
        STAGE_A((u + 1) & 15, 0, par ^ 1);
        bar();
        __builtin_amdgcn_s_setprio(1);
        #pragma unroll
        for (int m = 0; m < 4; m++)
            #pragma unroll
            for (int n = 0; n < 2; n++) {
                acc[m][n] = mfma16(af[m][0], bf[n][0], acc[m][n]);
                acc[m][n] = mfma16(af[m][1], bf[n][1], acc[m][n]);
            }
        __builtin_amdgcn_s_setprio(0);
        bar();

        #pragma unroll
        for (int n = 0; n < 2; n++) {
            bf[2 + n][0] = *(const bf16x8*)(pb + (2 + n) * 1024 + c0);
            bf[2 + n][1] = *(const bf16x8*)(pb + (2 + n) * 1024 + c1);
        }
        STAGE_A((u + 1) & 15, 1, par ^ 1);
        bar();
        __builtin_amdgcn_s_setprio(1);
        #pragma unroll
        for (int m = 0; m < 4; m++)
            #pragma unroll
            for (int n = 0; n < 2; n++) {
                acc[m][2 + n] = mfma16(af[m][0], bf[2 + n][0], acc[m][2 + n]);
                acc[m][2 + n] = mfma16(af[m][1], bf[2 + n][1], acc[m][2 + n]);
            }
        __builtin_amdgcn_s_setprio(0);
        bar();

        #pragma unroll
        for (int m = 0; m < 4; m++) {
            af[m][0] = *(const bf16x8*)(pa + (4 + m) * 1024 + c0);
            af[m][1] = *(const bf16x8*)(pa + (4 + m) * 1024 + c1);
        }
        STAGE_B((u + 2) & 15, 0, par);
        bar();
        __builtin_amdgcn_s_setprio(1);
        #pragma unroll
        for (int m = 0; m < 4; m++)
            #pragma unroll
            for (int n = 0; n < 2; n++) {
                acc[4 + m][2 + n] = mfma16(af[m][0], bf[2 + n][0], acc[4 + m][2 + n]);
                acc[4 + m][2 + n] = mfma16(af[m][1], bf[2 + n][1], acc[4 + m][2 + n]);
            }
        __builtin_amdgcn_s_setprio(0);
        bar();

        STAGE_B((u + 2) & 15, 1, par);
        VMCNT4();
        bar();
        __builtin_amdgcn_s_setprio(1);
        #pragma unroll
        for (int m = 0; m < 4; m++)
            #pragma unroll
            for (int n = 0; n < 2; n++) {
                acc[4 + m][n] = mfma16(af[m][0], bf[n][0], acc[4 + m][n]);
                acc[4 + m][n] = mfma16(af[m][1], bf[n][1], acc[4 + m][n]);
            }
        __builtin_amdgcn_s_setprio(0);
        bar();
    }
    VMCNT0();
    bar();

    // epilogue: bias + fp32 store via LDS, four 64-row passes
    float b4[4];
    #pragma unroll
    for (int nt = 0; nt < 4; nt++) b4[nt] = bias[n0 + wn * 64 + nt * 16 + ln];

    float* Ef = (float*)smem;   // [64][260]
    #pragma unroll
    for (int mq = 0; mq < 4; mq++) {
        if (mq) __syncthreads();
        if (wm == (mq >> 1)) {
            #pragma unroll
            for (int mt = 0; mt < 4; mt++)
                #pragma unroll
                for (int nt = 0; nt < 4; nt++)
                    #pragma unroll
                    for (int reg = 0; reg < 4; reg++)
                        Ef[(mt * 16 + quad * 4 + reg) * 260 + wn * 64 + nt * 16 + ln] =
                            acc[(mq & 1) * 4 + mt][nt][reg] + b4[nt];
        }
        __syncthreads();
        #pragma unroll
        for (int i = 0; i < 8; i++) {
            int idx = i * 512 + tid;
            int row = idx >> 6, ch = (idx & 63) * 4;
            float4 v = *(const float4*)(Ef + row * 260 + ch);
            *(float4*)(Out + (size_t)(m0 + mq * 64 + row) * DM + n0 + ch) = v;
        }
    }
}

// ---------------- Windowed attention ----------------------------------------
// WG = 512 threads / 8 waves = 128 queries x 1 head. grid (64, 16, 2).
// K and V^T staged once per WG via global_load_lds (XOR chunk swizzle).
__global__ __launch_bounds__(512, 4) void attn(
    const u16* __restrict__ QK,       // [16384][2048]
    const u16* __restrict__ Vt,       // [2048][8192]
    u16* __restrict__ AO)             // [16384][1024]
{
    __shared__ __align__(16) u16 Ks[256 * 64];     // [key][dim-chunk swizzled] 32KB (aliased by AOs)
    __shared__ __align__(16) u16 Vs[64 * 256];     // [dim][key-chunk swizzled] 32KB
    __shared__ __align__(16) u16 pbuf[8][512];     // per-wave P chunk, xor-swizzled

    const int blk = blockIdx.x;
    const int h   = blockIdx.y;
    const int b   = blockIdx.z;
    const int tid = threadIdx.x;
    const int lane = tid & 63, w = tid >> 6;
    const int quad = lane >> 4, ln = lane & 15;
    const int wstart = blk * 128 - 64;
    const size_t bbase = (size_t)b * L_SEQ;

    const u16* Kg = QK + 1024 + h * 64;
    const u16* Vg = Vt + (size_t)(b * 1024 + h * 64) * L_SEQ;

    // stage K: 256 rows x 8 chunks, chunk cg = cl ^ (row&7)
    #pragma unroll
    for (int i = 0; i < 4; i++) {
        int c = i * 512 + tid;
        int row = c >> 3, cl = c & 7, cg = cl ^ (row & 7);
        int kr = wstart + row;
        kr = kr < 0 ? 0 : (kr > L_SEQ - 1 ? L_SEQ - 1 : kr);
        gld_lds16(Kg + (size_t)(bbase + kr) * NQK + cg * 8, Ks + c * 8);
    }
    // stage V^T: 64 dim-rows x 32 key-chunks, chunk cg = kc ^ (d&7)
    #pragma unroll
    for (int i = 0; i < 4; i++) {
        int c = i * 512 + tid;
        int d = c >> 5, kc = c & 31, cg = kc ^ (d & 7);
        int key = wstart + cg * 8;
        key = key < 0 ? 0 : (key > L_SEQ - 8 ? L_SEQ - 8 : key);
        gld_lds16(Vg + (size_t)d * L_SEQ + key, Vs + c * 8);
    }

    // Q fragments (A-layout: m=ln, k=quad*8+j) direct from global
    const int qrow = blk * 128 + w * 16 + ln;
    const u16* qp = QK + (bbase + qrow) * NQK + h * 64 + quad * 8;
    bf16x8 aq0 = *(const bf16x8*)qp;
    bf16x8 aq1 = *(const bf16x8*)(qp + 32);
    __syncthreads();

    // scores: 16 n-tiles x 16 keys
    const f32x4 fz = {0.f, 0.f, 0.f, 0.f};
    f32x4 s[16];
    #pragma unroll
    for (int nt = 0; nt < 16; nt++) {
        int row = nt * 16 + ln;
        bf16x8 b0 = *(const bf16x8*)(Ks + row * 64 + ((quad       ^ (ln & 7)) * 8));
        bf16x8 b1 = *(const bf16x8*)(Ks + row * 64 + (((4 + quad) ^ (ln & 7)) * 8));
        f32x4 t = mfma16(aq0, b0, fz);
        t = mfma16(aq1, b1, t);
        s[nt] = t;
    }
    __syncthreads();   // all Ks reads done before AOs (alias) writes

    // softmax; row = quad*4+r, col key = wstart + nt*16 + ln
    const float SC = 0.125f * 1.4426950408889634f;   // /sqrt(64) * log2(e)
    float mr[4] = {-INFINITY, -INFINITY, -INFINITY, -INFINITY};
    #pragma unroll
    for (int nt = 0; nt < 16; nt++) {
        int key = wstart + nt * 16 + ln;
        bool valid = (key >= 0) && (key < L_SEQ);
        #pragma unroll
        for (int r = 0; r < 4; r++) {
            float v = valid ? s[nt][r] * SC : -INFINITY;
            s[nt][r] = v;
            mr[r] = fmaxf(mr[r], v);
        }
    }
    #pragma unroll
    for (int off = 1; off < 16; off <<= 1)
        #pragma unroll
        for (int r = 0; r < 4; r++) mr[r] = fmaxf(mr[r], __shfl_xor(mr[r], off));

    float lr[4] = {0.f, 0.f, 0.f, 0.f};
    #pragma unroll
    for (int nt = 0; nt < 16; nt++)
        #pragma unroll
        for (int r = 0; r < 4; r++) {
            float p = exp2f(s[nt][r] - mr[r]);   // exp2(-inf)=0 on masked cols
            s[nt][r] = p;
            lr[r] += p;
        }
    #pragma unroll
    for (int off = 1; off < 16; off <<= 1)
        #pragma unroll
        for (int r = 0; r < 4; r++) lr[r] += __shfl_xor(lr[r], off);
    float rl[4];
    #pragma unroll
    for (int r = 0; r < 4; r++) rl[r] = 1.f / lr[r];

    // PV: per 32-key chunk, C-layout -> A-layout via xor-swizzled per-wave LDS
    u16* pb = pbuf[w];
    f32x4 o[4] = {fz, fz, fz, fz};
    #pragma unroll
    for (int ks = 0; ks < 8; ks++) {
        #pragma unroll
        for (int n2 = 0; n2 < 2; n2++) {
            int nt = ks * 2 + n2;
            #pragma unroll
            for (int r = 0; r < 4; r++)
                pb[(quad * 4 + r) * 32 + ((n2 * 16 + ln) ^ (quad * 8))] = f2bf(s[nt][r]);
        }
        bf16x8 ap = *(const bf16x8*)(pb + ln * 32 + ((quad * 8) ^ (((ln >> 2) & 3) * 8)));
        #pragma unroll
        for (int dt = 0; dt < 4; dt++) {
            int d = dt * 16 + ln;
            bf16x8 vb = *(const bf16x8*)(Vs + d * 256 + (((ks * 4 + quad) ^ (ln & 7)) * 8));
            o[dt] = mfma16(ap, vb, o[dt]);
        }
    }

    // AO through LDS (alias Ks) for coalesced 16B stores
    u16* AOs = Ks;   // [128][72]
    #pragma unroll
    for (int dt = 0; dt < 4; dt++)
        #pragma unroll
        for (int r = 0; r < 4; r++)
            AOs[(w * 16 + quad * 4 + r) * 72 + dt * 16 + ln] = f2bf(o[dt][r] * rl[r]);
    __syncthreads();
    #pragma unroll
    for (int i = 0; i < 2; i++) {
        int c = i * 512 + tid;
        int row = c >> 3, ch = (c & 7) * 8;
        uint4 v = *(const uint4*)(AOs + row * 72 + ch);
        *(uint4*)(AO + (bbase + blk * 128 + row) * DM + h * 64 + ch) = v;
    }
}

// ---------------------------------------------------------------------------
extern "C" void kernel_launch(void* const* d_in, const int* in_sizes, int n_in,
                              void* d_out, int out_size, void* d_ws, size_t ws_size,
                              hipStream_t stream) {
    const float* x  = (const float*)d_in[0];
    const float* wq = (const float*)d_in[1];
    const float* wk = (const float*)d_in[2];
    const float* wv = (const float*)d_in[3];
    const float* wo = (const float*)d_in[4];
    const float* bo = (const float*)d_in[5];
    float* out = (float*)d_out;

    char* ws = (char*)d_ws;
    const size_t MB = 1024 * 1024;
    u16*   xb  = (u16*)ws;                       // 32 MB  [16384][1024] bf16
    u16*   fqk = (u16*)(ws + 32 * MB);           // 64 MB  [16384][2048] bf16 (Q|K)
    u16*   vt  = (u16*)(ws + 96 * MB);           // 32 MB  [2048][8192] bf16 (V^T)
    u16*   wf  = (u16*)(ws + 128 * MB);          // 6 MB   [3072][1024] bf16 (q,k,v stacked)
    float2* rt = (float2*)(ws + 134 * MB);       // 2 MB   [8192][32] cos/sin
    u16*   wob = (u16*)(ws + 136 * MB);          // 2 MB   [1024][1024] bf16
    u16*   aob = xb;   // x dead after fused GEMM; alias attention output over it

    cvt_bf16<<<8192, 256, 0, stream>>>(x, xb, 2097152);
    cvt_bf16<<<512, 256, 0, stream>>>(wq, wf, 131072);
    cvt_bf16<<<512, 256, 0, stream>>>(wk, wf + 1024 * 1024, 131072);
    cvt_bf16<<<512, 256, 0, stream>>>(wv, wf + 2 * 1024 * 1024, 131072);
    cvt_bf16<<<512, 256, 0, stream>>>(wo, wob, 131072);
    rope_tbl<<<1024, 256, 0, stream>>>(rt);

    gemm_qkv_fused<<<768, 512, 0, stream>>>(xb, wf, rt, fqk, vt);
    attn<<<dim3(64, 16, 2), 512, 0, stream>>>(fqk, vt, aob);
    gemm_oproj<<<256, 512, 0, stream>>>(aob, wob, bo, out);
}